// Round 10
// baseline (4676.395 us; speedup 1.0000x reference)
//
#include <hip/hip_runtime.h>
#include <hip/hip_fp16.h>

// Neural ODE (Dopri5, 64 steps), D=2048, H=8192.
// Round 9 design (resubmit; GPU-acquisition timeout, never ran):
// persistent kernel, 256 blocks x 512 threads (1 block/CU).
// vs round 8 (3.94 ms): (1) counter-based grid barrier w/ single release word
// (was: every block polls 256 flag lines), init kernel zeroes it; (2) mv2
// uses 16B LDS chunks (ds_read_b128) for W2+h (was 128x ds_read_b32/thread);
// (3) y/h staging as 8B atomic loads. W1 slice in registers (64 half2/thr),
// W2 slice in LDS (128 KB fp16). Relaxed agent atomics only (no L2-inval).

constexpr int D = 2048;
constexpr int H = 8192;
constexpr int NSTEPS = 64;
constexpr int NBLK = 256;
constexpr int NTHR = 512;

typedef unsigned long long ull;

__device__ __forceinline__ float waveReduce64(float v) {
    #pragma unroll
    for (int off = 32; off; off >>= 1) v += __shfl_down(v, off, 64);
    return v;
}

__device__ __forceinline__ void drainVM() {
    asm volatile("s_waitcnt vmcnt(0)" ::: "memory");
}

// Counter barrier: one atomicAdd per block on one line; finisher publishes
// epoch to a single release word; only tid 0 polls. All relaxed agent scope
// (no cache-invalidating ops). cnt/rel zeroed by k_init each call, so no
// poison-dependence. Capped spin fails loud (wrong answer) instead of hanging.
__device__ __forceinline__ void gridBarrier(int* cnt, int* rel, int gen, int tid) {
    drainVM();          // per-wave: all global stores drained to coherence point
    __syncthreads();    // whole block's data visible before the arrival add
    if (tid == 0) {
        int old = __hip_atomic_fetch_add(cnt, 1, __ATOMIC_RELAXED,
                                         __HIP_MEMORY_SCOPE_AGENT);
        if (old == gen * NBLK - 1) {
            __hip_atomic_store(rel, gen, __ATOMIC_RELAXED,
                               __HIP_MEMORY_SCOPE_AGENT);
        } else {
            int spin = 0;
            while (__hip_atomic_load(rel, __ATOMIC_RELAXED,
                                     __HIP_MEMORY_SCOPE_AGENT) < gen) {
                if (++spin > (1 << 22)) break;
                __builtin_amdgcn_s_sleep(1);
            }
        }
    }
    __syncthreads();
    asm volatile("" ::: "memory");
}

__global__ void k_init(int* cnt, int* rel) {
    if (threadIdx.x == 0) {
        __hip_atomic_store(cnt, 0, __ATOMIC_RELAXED, __HIP_MEMORY_SCOPE_AGENT);
        __hip_atomic_store(rel, 0, __ATOMIC_RELAXED, __HIP_MEMORY_SCOPE_AGENT);
    }
}

__global__ __launch_bounds__(NTHR, 2) void k_ode(
    const float* __restrict__ x,  const float* __restrict__ W1,
    const float* __restrict__ wt, const float* __restrict__ b1,
    const float* __restrict__ W2, const float* __restrict__ b2,
    float* __restrict__ out, float* __restrict__ yi_g,
    unsigned int* __restrict__ h_g, int* __restrict__ cnt, int* __restrict__ rel)
{
    // chunk c of a row = elements 8c..8c+7 packed as 4 half2 (16 B)
    __shared__ uint4 w2lds[8][1024];   // 128 KB: block's 8 W2 rows
    __shared__ uint4 hlds4[1024];      //  16 KB: h (8192 fp16)
    __shared__ float ylds[D];          //   8 KB

    const int tid = threadIdx.x, bid = blockIdx.x;
    const int wave = tid >> 6, lane = tid & 63;

    // ---- one-time: W1 slice -> registers ----
    // wave owns W1 rows r0..r0+3; lane owns float4 chunks j4*64+lane (j4<8),
    // i.e. elements 4*(j4*64+lane)..+3 -> half2s w1f[r][2*j4], w1f[r][2*j4+1]
    const int r0 = bid * 32 + wave * 4;
    __half2 w1f[4][16];
    #pragma unroll
    for (int r = 0; r < 4; ++r) {
        const float4* s4 = (const float4*)(W1 + (size_t)(r0 + r) * D);
        #pragma unroll
        for (int j4 = 0; j4 < 8; ++j4) {
            float4 a = s4[j4 * 64 + lane];            // coalesced 1KB/wave
            w1f[r][2 * j4]     = __floats2half2_rn(a.x, a.y);
            w1f[r][2 * j4 + 1] = __floats2half2_rn(a.z, a.w);
        }
    }
    // ---- one-time: W2 slice -> LDS, 16B-chunk layout ----
    const int row2 = bid * 8 + wave;
    {
        const float4* s4 = (const float4*)(W2 + (size_t)row2 * H);
        #pragma unroll
        for (int it = 0; it < 16; ++it) {
            const int c = it * 64 + lane;             // chunk id 0..1023
            float4 f0 = s4[2 * c];                    // elements 8c..8c+3
            float4 f1 = s4[2 * c + 1];                // elements 8c+4..8c+7
            uint4 p;
            p.x = __builtin_bit_cast(unsigned, __floats2half2_rn(f0.x, f0.y));
            p.y = __builtin_bit_cast(unsigned, __floats2half2_rn(f0.z, f0.w));
            p.z = __builtin_bit_cast(unsigned, __floats2half2_rn(f1.x, f1.y));
            p.w = __builtin_bit_cast(unsigned, __floats2half2_rn(f1.z, f1.w));
            w2lds[wave][c] = p;
        }
    }
    const float wt0 = wt[r0], wt1 = wt[r0+1], wt2 = wt[r0+2], wt3 = wt[r0+3];
    const float b10 = b1[r0], b11 = b1[r0+1], b12 = b1[r0+2], b13 = b1[r0+3];

    float yreg = x[row2];                // tableau state, lane 0 of each wave
    const float b2r = b2[row2];
    float k0 = 0, k1 = 0, k2 = 0, k3 = 0, k4 = 0;

    const ull* yg64 = (const ull*)yi_g;
    const ull* hg64 = (const ull*)h_g;

    constexpr float dt = 1.0f / 64.0f;
    int gen = 1;

    #pragma unroll 1
    for (int step = 0; step < NSTEPS; ++step) {
        const float t = step * dt;
        #pragma unroll
        for (int st = 0; st < 6; ++st) {
            constexpr float Cc[6] = {0.f, 0.2f, 0.3f, 0.8f, 8.f/9.f, 1.f};
            const float s = 1.0f - (t + Cc[st] * dt);

            // ---- stage yi (2048 f32) -> LDS ----
            if (step == 0 && st == 0) {
                ((float4*)ylds)[tid] = ((const float4*)x)[tid];
            } else {
                #pragma unroll
                for (int k = 0; k < 2; ++k)
                    ((ull*)ylds)[tid + k * 512] = __hip_atomic_load(
                        yg64 + tid + k * 512, __ATOMIC_RELAXED,
                        __HIP_MEMORY_SCOPE_AGENT);
            }
            __syncthreads();

            // ---- mv1: 4 W1 rows per wave (weights in registers) ----
            float a0 = 0, a1 = 0, a2 = 0, a3 = 0;
            #pragma unroll
            for (int j4 = 0; j4 < 8; ++j4) {
                float4 yv = ((const float4*)ylds)[j4 * 64 + lane];
                float2 f;
                f = __half22float2(w1f[0][2*j4]);   a0 = fmaf(f.x, yv.x, fmaf(f.y, yv.y, a0));
                f = __half22float2(w1f[0][2*j4+1]); a0 = fmaf(f.x, yv.z, fmaf(f.y, yv.w, a0));
                f = __half22float2(w1f[1][2*j4]);   a1 = fmaf(f.x, yv.x, fmaf(f.y, yv.y, a1));
                f = __half22float2(w1f[1][2*j4+1]); a1 = fmaf(f.x, yv.z, fmaf(f.y, yv.w, a1));
                f = __half22float2(w1f[2][2*j4]);   a2 = fmaf(f.x, yv.x, fmaf(f.y, yv.y, a2));
                f = __half22float2(w1f[2][2*j4+1]); a2 = fmaf(f.x, yv.z, fmaf(f.y, yv.w, a2));
                f = __half22float2(w1f[3][2*j4]);   a3 = fmaf(f.x, yv.x, fmaf(f.y, yv.y, a3));
                f = __half22float2(w1f[3][2*j4+1]); a3 = fmaf(f.x, yv.z, fmaf(f.y, yv.w, a3));
            }
            a0 = waveReduce64(a0); a1 = waveReduce64(a1);
            a2 = waveReduce64(a2); a3 = waveReduce64(a3);
            if (lane == 0) {
                float h0 = tanhf(fmaf(s, wt0, a0 + b10));
                float h1 = tanhf(fmaf(s, wt1, a1 + b11));
                float h2 = tanhf(fmaf(s, wt2, a2 + b12));
                float h3 = tanhf(fmaf(s, wt3, a3 + b13));
                __half2 lo = __floats2half2_rn(h0, h1);
                __half2 hi = __floats2half2_rn(h2, h3);
                ull pv = ((ull)__builtin_bit_cast(unsigned, hi) << 32) |
                          (ull)__builtin_bit_cast(unsigned, lo);
                __hip_atomic_store((ull*)h_g + (bid * 8 + wave), pv,
                                   __ATOMIC_RELAXED, __HIP_MEMORY_SCOPE_AGENT);
            }
            gridBarrier(cnt, rel, gen++, tid);

            // ---- stage h (8192 fp16 = 2048 ull) -> LDS ----
            #pragma unroll
            for (int k = 0; k < 4; ++k)
                ((ull*)hlds4)[tid + k * 512] = __hip_atomic_load(
                    hg64 + tid + k * 512, __ATOMIC_RELAXED,
                    __HIP_MEMORY_SCOPE_AGENT);
            __syncthreads();

            // ---- mv2: 1 W2 row per wave, 16B LDS chunks ----
            float acc = 0.f;
            #pragma unroll
            for (int j2 = 0; j2 < 16; ++j2) {
                const int c = j2 * 64 + lane;
                uint4 wv = w2lds[wave][c];
                uint4 hv = hlds4[c];
                float2 wf, hf;
                wf = __half22float2(__builtin_bit_cast(__half2, wv.x));
                hf = __half22float2(__builtin_bit_cast(__half2, hv.x));
                acc = fmaf(wf.x, hf.x, fmaf(wf.y, hf.y, acc));
                wf = __half22float2(__builtin_bit_cast(__half2, wv.y));
                hf = __half22float2(__builtin_bit_cast(__half2, hv.y));
                acc = fmaf(wf.x, hf.x, fmaf(wf.y, hf.y, acc));
                wf = __half22float2(__builtin_bit_cast(__half2, wv.z));
                hf = __half22float2(__builtin_bit_cast(__half2, hv.z));
                acc = fmaf(wf.x, hf.x, fmaf(wf.y, hf.y, acc));
                wf = __half22float2(__builtin_bit_cast(__half2, wv.w));
                hf = __half22float2(__builtin_bit_cast(__half2, hv.w));
                acc = fmaf(wf.x, hf.x, fmaf(wf.y, hf.y, acc));
            }
            acc = waveReduce64(acc);

            // ---- tableau epilogue: lane 0 of the owning wave ----
            if (lane == 0) {
                const float k = -(acc + b2r);
                float yo = yreg;
                if (st == 0) { k0 = k;
                    yo = fmaf(dt * 0.2f, k0, yreg); }
                else if (st == 1) { k1 = k;
                    yo = yreg + dt * (3.f/40.f*k0 + 9.f/40.f*k1); }
                else if (st == 2) { k2 = k;
                    yo = yreg + dt * (44.f/45.f*k0 - 56.f/15.f*k1 + 32.f/9.f*k2); }
                else if (st == 3) { k3 = k;
                    yo = yreg + dt * (19372.f/6561.f*k0 - 25360.f/2187.f*k1
                                    + 64448.f/6561.f*k2 - 212.f/729.f*k3); }
                else if (st == 4) { k4 = k;
                    yo = yreg + dt * (9017.f/3168.f*k0 - 355.f/33.f*k1
                                    + 46732.f/5247.f*k2 + 49.f/176.f*k3
                                    - 5103.f/18656.f*k4); }
                else {
                    yreg = yreg + dt * (35.f/384.f*k0 + 500.f/1113.f*k2
                                      + 125.f/192.f*k3 - 2187.f/6784.f*k4
                                      + 11.f/84.f*k);
                    yo = yreg;
                    if (step == NSTEPS - 1) out[row2] = yreg;
                }
                __hip_atomic_store(yi_g + row2, yo, __ATOMIC_RELAXED,
                                   __HIP_MEMORY_SCOPE_AGENT);
            }
            if (!(step == NSTEPS - 1 && st == 5))   // last barrier elided
                gridBarrier(cnt, rel, gen++, tid);
        }
    }
}

extern "C" void kernel_launch(void* const* d_in, const int* in_sizes, int n_in,
                              void* d_out, int out_size, void* d_ws, size_t ws_size,
                              hipStream_t stream) {
    const float* x  = (const float*)d_in[0];
    const float* W1 = (const float*)d_in[1];
    const float* wt = (const float*)d_in[2];
    const float* b1 = (const float*)d_in[3];
    const float* W2 = (const float*)d_in[4];
    const float* b2 = (const float*)d_in[5];
    float* out = (float*)d_out;

    float*        ws   = (float*)d_ws;
    float*        yi_g = ws;                         // [2048] f32
    unsigned int* h_g  = (unsigned int*)(ws + D);    // [4096] u32 (8192 fp16)
    int*          cnt  = (int*)(ws + D + 4096);      // arrival counter
    int*          rel  = cnt + 64;                   // release word (diff line)

    hipLaunchKernelGGL(k_init, dim3(1), dim3(64), 0, stream, cnt, rel);
    hipLaunchKernelGGL(k_ode, dim3(NBLK), dim3(NTHR), 0, stream,
                       x, W1, wt, b1, W2, b2, out, yi_g, h_g, cnt, rel);
}